// Round 3
// baseline (1188.512 us; speedup 1.0000x reference)
//
#include <hip/hip_runtime.h>
#include <stdint.h>
#include <stddef.h>

#define NTOK 8192
#define DDIM 1024

// Plan A: Sb + SbT materialized (leaky scores, fp16), exp in place. ~321 MB.
#define WS_A 336592896ull
// Plan C: fully chunked over j. 65 MB + 2*(8192*CHJ*2).
#define WS_C2048 135266304ull
#define WS_C1024 101711872ull
#define WS_C512   84934656ull

using f16   = _Float16;
using f16x8 = __attribute__((ext_vector_type(8))) _Float16;
using f32x4 = __attribute__((ext_vector_type(4))) float;

// ---------- async global->LDS (16B), linear LDS dest, swizzled global src ----------
__device__ __forceinline__ void gload16(const void* g, void* l) {
  __builtin_amdgcn_global_load_lds(
      (const __attribute__((address_space(1))) void*)g,
      (__attribute__((address_space(3))) void*)l, 16, 0, 0);
}

// Stage 128 x 64 f16 tile from row-major src (ld elems) into linear LDS [128][64].
// LDS 16B-chunk (r,c) holds global chunk (r, c ^ (r&7))  (rule #21: swizzle src+read).
__device__ __forceinline__ void stage_tile(const f16* __restrict__ src, int ld,
                                           int row0, int k0, f16* lds, int tid) {
#pragma unroll
  for (int base = 0; base < 1024; base += 256) {
    const int cl = base + tid;
    const int r = cl >> 3;
    const int cs = (cl & 7) ^ (r & 7);
    gload16(src + (size_t)(row0 + r) * ld + k0 + cs * 8, (char*)lds + (size_t)cl * 16);
  }
}

// Read one 8-f16 operand fragment (row r, k-chunk kc) with matching swizzle.
__device__ __forceinline__ f16x8 frag_ld(const f16* lds, int r, int kc) {
  const int c = kc ^ (r & 7);
  return *(const f16x8*)((const char*)lds + r * 128 + c * 16);
}

// XCD-aware chunked swizzle, bijective when nwg % 8 == 0.
__device__ __forceinline__ int xcd_swz(int bid, int nwg) {
  return (bid & 7) * (nwg >> 3) + (bid >> 3);
}

// ---------- prep: f32 -> f16, plus transposed f16 copy ----------
__global__ void prep_kernel(const float* __restrict__ inA, const float* __restrict__ inB,
                            f16* __restrict__ nA, f16* __restrict__ tA,
                            f16* __restrict__ nB, f16* __restrict__ tB) {
  const float* in = blockIdx.z ? inB : inA;
  f16* nrm = blockIdx.z ? nB : nA;
  f16* trp = blockIdx.z ? tB : tA;
  __shared__ float tile[32][33];
  const int c0 = blockIdx.x * 32;
  const int r0 = blockIdx.y * 32;
  const int tx = threadIdx.x, ty = threadIdx.y;
#pragma unroll
  for (int rr = 0; rr < 32; rr += 8) {
    const int r = r0 + rr + ty;
    const float v = in[(size_t)r * DDIM + c0 + tx];
    tile[rr + ty][tx] = v;
    nrm[(size_t)r * DDIM + c0 + tx] = (f16)v;
  }
  __syncthreads();
#pragma unroll
  for (int rr = 0; rr < 32; rr += 8) {
    trp[(size_t)(c0 + rr + ty) * NTOK + r0 + tx] = (f16)tile[tx][rr + ty];
  }
}

// ---------- core MFMA macro-body: 128x128 tile over K, NT layout ----------
#define GEMM_CORE(Asrc, lda, Bsrc, ldb, KLEN)                                         \
  for (int k0 = 0; k0 < (KLEN); k0 += 64) {                                           \
    __syncthreads();                                                                  \
    stage_tile(Asrc, lda, row0, k0, Al, tid);                                         \
    stage_tile(Bsrc, ldb, col0, k0, Bl, tid);                                         \
    __syncthreads();                                                                  \
    _Pragma("unroll")                                                                 \
    for (int kk = 0; kk < 2; ++kk) {                                                  \
      f16x8 a[4], b[4];                                                               \
      _Pragma("unroll")                                                               \
      for (int m = 0; m < 4; ++m) a[m] = frag_ld(Al, wr + m * 16 + l15, kk * 4 + lg); \
      _Pragma("unroll")                                                               \
      for (int n = 0; n < 4; ++n) b[n] = frag_ld(Bl, wc + n * 16 + l15, kk * 4 + lg); \
      _Pragma("unroll")                                                               \
      for (int m = 0; m < 4; ++m)                                                     \
        _Pragma("unroll")                                                             \
        for (int n = 0; n < 4; ++n)                                                   \
          acc[m][n] = __builtin_amdgcn_mfma_f32_16x16x32_f16(a[m], b[n], acc[m][n], 0, 0, 0); \
    }                                                                                 \
  }

// ---------- Plan A: S-GEMM, leaky, row/col sum-sq, store Sb and SbT (f16) ----------
__global__ __launch_bounds__(256, 2)
void sgemm_kernel(const f16* __restrict__ A, const f16* __restrict__ B,
                  float* __restrict__ row_ss, float* __restrict__ col_ss,
                  f16* __restrict__ Sb, f16* __restrict__ SbT) {
  __shared__ __align__(16) char smem[128 * 136 * 2];  // staging (32KB) unioned with repack
  f16* Al = (f16*)smem;
  f16* Bl = (f16*)(smem + 16384);
  f16* RP = (f16*)smem;  // 128 x 136 f16
  const int tid = threadIdx.x;
  const int lane = tid & 63, wid = tid >> 6;
  const int wr = (wid >> 1) * 64, wc = (wid & 1) * 64;
  const int l15 = lane & 15, lg = lane >> 4;
  const int swz = xcd_swz(blockIdx.x, 4096);
  const int row0 = (swz & 63) * 128, col0 = (swz >> 6) * 128;
  f32x4 acc[4][4];
#pragma unroll
  for (int m = 0; m < 4; ++m)
#pragma unroll
    for (int n = 0; n < 4; ++n) acc[m][n] = (f32x4){0.f, 0.f, 0.f, 0.f};

  GEMM_CORE(A, DDIM, B, DDIM, DDIM)

  // leaky in place
#pragma unroll
  for (int m = 0; m < 4; ++m)
#pragma unroll
    for (int n = 0; n < 4; ++n)
#pragma unroll
      for (int q = 0; q < 4; ++q) {
        const float v = acc[m][n][q];
        acc[m][n][q] = v > 0.f ? v : 0.1f * v;
      }
  // sum-of-squares reductions (registers + shfl only)
  float cpart[4] = {0.f, 0.f, 0.f, 0.f};
#pragma unroll
  for (int m = 0; m < 4; ++m) {
    float rpart[4] = {0.f, 0.f, 0.f, 0.f};
#pragma unroll
    for (int n = 0; n < 4; ++n) {
#pragma unroll
      for (int q = 0; q < 4; ++q) {
        const float v2 = acc[m][n][q] * acc[m][n][q];
        rpart[q] += v2;
        cpart[n] += v2;
      }
    }
#pragma unroll
    for (int q = 0; q < 4; ++q) {
      float s = rpart[q];
      s += __shfl_xor(s, 1, 64);
      s += __shfl_xor(s, 2, 64);
      s += __shfl_xor(s, 4, 64);
      s += __shfl_xor(s, 8, 64);
      if (l15 == 0) atomicAdd(&row_ss[row0 + wr + m * 16 + lg * 4 + q], s);
    }
  }
#pragma unroll
  for (int n = 0; n < 4; ++n) {
    float s = cpart[n];
    s += __shfl_xor(s, 16, 64);
    s += __shfl_xor(s, 32, 64);
    if (lg == 0) atomicAdd(&col_ss[col0 + wc + n * 16 + l15], s);
  }
  // ---- repack + coalesced store: Sb[i,j] ----
  __syncthreads();
#pragma unroll
  for (int m = 0; m < 4; ++m)
#pragma unroll
    for (int n = 0; n < 4; ++n)
#pragma unroll
      for (int q = 0; q < 4; ++q)
        RP[(wr + m * 16 + lg * 4 + q) * 136 + wc + n * 16 + l15] = (f16)acc[m][n][q];
  __syncthreads();
#pragma unroll
  for (int it = 0; it < 8; ++it) {
    const int r = it * 16 + (tid >> 4);
    const int c8 = (tid & 15) * 8;
    *(f16x8*)(Sb + (size_t)(row0 + r) * NTOK + col0 + c8) = *(const f16x8*)(RP + r * 136 + c8);
  }
  __syncthreads();
  // ---- transposed repack + coalesced store: SbT[j,i] ----
#pragma unroll
  for (int m = 0; m < 4; ++m)
#pragma unroll
    for (int n = 0; n < 4; ++n)
#pragma unroll
      for (int q = 0; q < 4; ++q)
        RP[(wc + n * 16 + l15) * 136 + wr + m * 16 + lg * 4 + q] = (f16)acc[m][n][q];
  __syncthreads();
#pragma unroll
  for (int it = 0; it < 8; ++it) {
    const int r = it * 16 + (tid >> 4);   // local j
    const int c8 = (tid & 15) * 8;        // local i
    *(f16x8*)(SbT + (size_t)(col0 + r) * NTOK + row0 + c8) = *(const f16x8*)(RP + r * 136 + c8);
  }
}

// ---------- scales: 6*log2(e) / (sqrt(ss)+eps) ----------
__global__ void scales_kernel(const float* __restrict__ row_ss, const float* __restrict__ col_ss,
                              float* __restrict__ s1p, float* __restrict__ s2p) {
  const int i = blockIdx.x * 256 + threadIdx.x;
  const float c = 6.0f * 1.4426950408889634f;
  s1p[i] = c / (sqrtf(row_ss[i]) + 1e-8f);
  s2p[i] = c / (sqrtf(col_ss[i]) + 1e-8f);
}

// ---------- Plan A: in-place P = exp2(S*scale_row) per row, Z = row sum ----------
__global__ __launch_bounds__(256, 8)
void expz_kernel(f16* __restrict__ Mr, f16* __restrict__ Mc,
                 const float* __restrict__ s1p, const float* __restrict__ s2p,
                 float* __restrict__ Z1, float* __restrict__ Z2) {
  f16* M = blockIdx.z ? Mc : Mr;
  const float* scv = blockIdx.z ? s2p : s1p;
  float* Z = blockIdx.z ? Z2 : Z1;
  const int wid = threadIdx.x >> 6, lane = threadIdx.x & 63;
  const int row = blockIdx.x * 4 + wid;
  const float s = scv[row];
  f16* rp = M + (size_t)row * NTOK;
  float acc = 0.f;
#pragma unroll
  for (int c = 0; c < 16; ++c) {
    f16x8* p = (f16x8*)(rp + (c * 64 + lane) * 8);
    f16x8 v = *p;
    f16x8 o;
#pragma unroll
    for (int e = 0; e < 8; ++e) {
      o[e] = (f16)exp2f((float)v[e] * s);
      acc += (float)o[e];  // sum the f16-rounded value: consistent with GEMM input
    }
    *p = o;
  }
#pragma unroll
  for (int d = 1; d < 64; d <<= 1) acc += __shfl_xor(acc, d, 64);
  if (lane == 0) Z[row] = acc;
}

// ---------- Plan C: pass1 (S-GEMM + row/col sum-sq only) ----------
__global__ __launch_bounds__(256, 2)
void pass1_kernel(const f16* __restrict__ A, const f16* __restrict__ B,
                  float* __restrict__ row_ss, float* __restrict__ col_ss) {
  __shared__ __align__(16) f16 Al[128 * 64];
  __shared__ __align__(16) f16 Bl[128 * 64];
  const int tid = threadIdx.x;
  const int lane = tid & 63, wid = tid >> 6;
  const int wr = (wid >> 1) * 64, wc = (wid & 1) * 64;
  const int l15 = lane & 15, lg = lane >> 4;
  const int swz = xcd_swz(blockIdx.x, 4096);
  const int row0 = (swz & 63) * 128, col0 = (swz >> 6) * 128;
  f32x4 acc[4][4];
#pragma unroll
  for (int m = 0; m < 4; ++m)
#pragma unroll
    for (int n = 0; n < 4; ++n) acc[m][n] = (f32x4){0.f, 0.f, 0.f, 0.f};

  GEMM_CORE(A, DDIM, B, DDIM, DDIM)

  float cpart[4] = {0.f, 0.f, 0.f, 0.f};
#pragma unroll
  for (int m = 0; m < 4; ++m) {
    float rpart[4] = {0.f, 0.f, 0.f, 0.f};
#pragma unroll
    for (int n = 0; n < 4; ++n) {
#pragma unroll
      for (int q = 0; q < 4; ++q) {
        float v = acc[m][n][q];
        v = v > 0.f ? v : 0.1f * v;
        const float v2 = v * v;
        rpart[q] += v2;
        cpart[n] += v2;
      }
    }
#pragma unroll
    for (int q = 0; q < 4; ++q) {
      float s = rpart[q];
      s += __shfl_xor(s, 1, 64);
      s += __shfl_xor(s, 2, 64);
      s += __shfl_xor(s, 4, 64);
      s += __shfl_xor(s, 8, 64);
      if (l15 == 0) atomicAdd(&row_ss[row0 + wr + m * 16 + lg * 4 + q], s);
    }
  }
#pragma unroll
  for (int n = 0; n < 4; ++n) {
    float s = cpart[n];
    s += __shfl_xor(s, 16, 64);
    s += __shfl_xor(s, 32, 64);
    if (lg == 0) atomicAdd(&col_ss[col0 + wc + n * 16 + l15], s);
  }
}

// ---------- Plan C: per-j-chunk recompute; emit P1c [NTOK x CHJ] + P2c [CHJ x NTOK], Z sums ----------
__global__ __launch_bounds__(256, 2)
void pass2c_kernel(const f16* __restrict__ A, const f16* __restrict__ B,
                   const float* __restrict__ s1p, const float* __restrict__ s2p,
                   f16* __restrict__ P1c, f16* __restrict__ P2c,
                   float* __restrict__ Z1, float* __restrict__ Z2, int j0, int CHJ) {
  __shared__ __align__(16) char smem[128 * 136 * 2];
  f16* Al = (f16*)smem;
  f16* Bl = (f16*)(smem + 16384);
  f16* RP = (f16*)smem;
  const int tid = threadIdx.x;
  const int lane = tid & 63, wid = tid >> 6;
  const int wr = (wid >> 1) * 64, wc = (wid & 1) * 64;
  const int l15 = lane & 15, lg = lane >> 4;
  const int row0 = blockIdx.x * 128;            // global i
  const int col0loc = blockIdx.y * 128;         // local j within chunk
  const int col0 = j0 + col0loc;                // global j (for B operand + scales)
  f32x4 acc[4][4];
#pragma unroll
  for (int m = 0; m < 4; ++m)
#pragma unroll
    for (int n = 0; n < 4; ++n) acc[m][n] = (f32x4){0.f, 0.f, 0.f, 0.f};

  GEMM_CORE(A, DDIM, B, DDIM, DDIM)

#pragma unroll
  for (int m = 0; m < 4; ++m)
#pragma unroll
    for (int n = 0; n < 4; ++n)
#pragma unroll
      for (int q = 0; q < 4; ++q) {
        const float v = acc[m][n][q];
        acc[m][n][q] = v > 0.f ? v : 0.1f * v;
      }
  float sr[4][4], sc[4];
#pragma unroll
  for (int m = 0; m < 4; ++m)
#pragma unroll
    for (int q = 0; q < 4; ++q) sr[m][q] = s1p[row0 + wr + m * 16 + lg * 4 + q];
#pragma unroll
  for (int n = 0; n < 4; ++n) sc[n] = s2p[col0 + wc + n * 16 + l15];

  __syncthreads();
  // ---- round A: p1 = exp2(s*srow), repack -> coalesced P1c rows + Z1 ----
#pragma unroll
  for (int m = 0; m < 4; ++m)
#pragma unroll
    for (int n = 0; n < 4; ++n)
#pragma unroll
      for (int q = 0; q < 4; ++q) {
        const float p = exp2f(acc[m][n][q] * sr[m][q]);
        RP[(wr + m * 16 + lg * 4 + q) * 136 + wc + n * 16 + l15] = (f16)p;
      }
  __syncthreads();
#pragma unroll
  for (int it = 0; it < 8; ++it) {
    const int r = it * 16 + (tid >> 4);
    const int c8 = (tid & 15) * 8;
    const f16x8 v = *(const f16x8*)(RP + r * 136 + c8);
    float s = 0.f;
#pragma unroll
    for (int e = 0; e < 8; ++e) s += (float)v[e];
    *(f16x8*)(P1c + (size_t)(row0 + r) * CHJ + col0loc + c8) = v;
    s += __shfl_xor(s, 1, 64);
    s += __shfl_xor(s, 2, 64);
    s += __shfl_xor(s, 4, 64);
    s += __shfl_xor(s, 8, 64);
    if ((tid & 15) == 0) atomicAdd(&Z1[row0 + r], s);
  }
  __syncthreads();
  // ---- round B: p2 = exp2(s*scol), transposed repack -> P2c[jl, i] + Z2 ----
#pragma unroll
  for (int m = 0; m < 4; ++m)
#pragma unroll
    for (int n = 0; n < 4; ++n)
#pragma unroll
      for (int q = 0; q < 4; ++q) {
        const float p = exp2f(acc[m][n][q] * sc[n]);
        RP[(wc + n * 16 + l15) * 136 + wr + m * 16 + lg * 4 + q] = (f16)p;
      }
  __syncthreads();
#pragma unroll
  for (int it = 0; it < 8; ++it) {
    const int r = it * 16 + (tid >> 4);   // local j
    const int c8 = (tid & 15) * 8;        // local i base
    const f16x8 v = *(const f16x8*)(RP + r * 136 + c8);
    float s = 0.f;
#pragma unroll
    for (int e = 0; e < 8; ++e) s += (float)v[e];
    *(f16x8*)(P2c + (size_t)(col0loc + r) * NTOK + row0 + c8) = v;
    s += __shfl_xor(s, 1, 64);
    s += __shfl_xor(s, 2, 64);
    s += __shfl_xor(s, 4, 64);
    s += __shfl_xor(s, 8, 64);
    if ((tid & 15) == 0) atomicAdd(&Z2[col0 + r], s);
  }
}

// ---------- output GEMM: C tile (+)= A[M,K] @ Bt[N,K]^T, C f32 ld=DDIM. 1D grid, swizzled ----------
__global__ __launch_bounds__(256, 2)
void gemm_out_kernel(const f16* __restrict__ A, int lda,
                     const f16* __restrict__ Bt, int ldb,
                     float* __restrict__ C, int K, int beta, int nwg) {
  __shared__ __align__(16) f16 Al[128 * 64];
  __shared__ __align__(16) f16 Bl[128 * 64];
  const int tid = threadIdx.x;
  const int lane = tid & 63, wid = tid >> 6;
  const int wr = (wid >> 1) * 64, wc = (wid & 1) * 64;
  const int l15 = lane & 15, lg = lane >> 4;
  const int swz = xcd_swz(blockIdx.x, nwg);
  const int row0 = (swz >> 3) * 128, col0 = (swz & 7) * 128;
  f32x4 acc[4][4];
#pragma unroll
  for (int m = 0; m < 4; ++m)
#pragma unroll
    for (int n = 0; n < 4; ++n) acc[m][n] = (f32x4){0.f, 0.f, 0.f, 0.f};

  GEMM_CORE(A, lda, Bt, ldb, K)

#pragma unroll
  for (int m = 0; m < 4; ++m)
#pragma unroll
    for (int n = 0; n < 4; ++n) {
      const int ccol = col0 + wc + n * 16 + l15;
#pragma unroll
      for (int q = 0; q < 4; ++q) {
        const int crow = row0 + wr + m * 16 + lg * 4 + q;
        const size_t idx = (size_t)crow * DDIM + ccol;
        const float v = acc[m][n][q];
        C[idx] = beta ? C[idx] + v : v;
      }
    }
}

// ---------- final normalization by 1/Z ----------
__global__ void norm_kernel(float* __restrict__ out, const float* __restrict__ Z1,
                            const float* __restrict__ Z2) {
  const size_t idx = (size_t)blockIdx.x * 256 + threadIdx.x;  // float4 index
  const size_t e = idx * 4;
  const size_t half = (size_t)NTOK * DDIM;
  const float* Z = (e < half) ? Z1 : Z2;
  const int r = (int)((e >> 10) & (NTOK - 1));
  const float inv = 1.0f / Z[r];
  f32x4* o = (f32x4*)out;
  f32x4 v = o[idx];
  v.x *= inv; v.y *= inv; v.z *= inv; v.w *= inv;
  o[idx] = v;
}

__global__ void fill_kernel(float* __restrict__ out, float v, size_t n) {
  const size_t i = (size_t)blockIdx.x * 256 + threadIdx.x;
  if (i < n) out[i] = v;
}

extern "C" void kernel_launch(void* const* d_in, const int* in_sizes, int n_in,
                              void* d_out, int out_size, void* d_ws, size_t ws_size,
                              hipStream_t stream) {
  const float* im = (const float*)d_in[0];
  const float* aud = (const float*)d_in[1];
  float* out = (float*)d_out;
  char* ws = (char*)d_ws;

  // shared low-workspace layout
  f16* im_h  = (f16*)(ws);
  f16* aud_h = (f16*)(ws + (size_t)16777216);
  f16* imT   = (f16*)(ws + (size_t)33554432);
  f16* audT  = (f16*)(ws + (size_t)50331648);
  float* row_ss = (float*)(ws + (size_t)67108864);
  float* col_ss = (float*)(ws + (size_t)67108864 + 32768);
  float* Z1     = (float*)(ws + (size_t)67108864 + 65536);
  float* Z2     = (float*)(ws + (size_t)67108864 + 98304);
  float* s1p    = (float*)(ws + (size_t)67108864 + 131072);
  float* s2p    = (float*)(ws + (size_t)67108864 + 163840);

  if (ws_size >= WS_A) {
    // ---------------- Plan A: single S-GEMM, materialized Sb/SbT ----------------
    f16* Sb  = (f16*)(ws + (size_t)68157440);   // 8192x8192 f16 (128 MB), becomes P1 in place
    f16* SbT = (f16*)(ws + (size_t)202375168);  // transpose, becomes P2 in place

    hipMemsetAsync(row_ss, 0, 2 * NTOK * sizeof(float), stream);
    prep_kernel<<<dim3(32, 256, 2), dim3(32, 8), 0, stream>>>(im, aud, im_h, imT, aud_h, audT);
    sgemm_kernel<<<4096, 256, 0, stream>>>(im_h, aud_h, row_ss, col_ss, Sb, SbT);
    scales_kernel<<<NTOK / 256, 256, 0, stream>>>(row_ss, col_ss, s1p, s2p);
    expz_kernel<<<dim3(NTOK / 4, 1, 2), 256, 0, stream>>>(Sb, SbT, s1p, s2p, Z1, Z2);
    // im_rec (unnormalized) = P1 @ audT^T
    gemm_out_kernel<<<512, 256, 0, stream>>>(Sb, NTOK, audT, NTOK, out, NTOK, 0, 512);
    // aud_rec (unnormalized) = P2 @ imT^T
    gemm_out_kernel<<<512, 256, 0, stream>>>(SbT, NTOK, imT, NTOK,
                                             out + (size_t)NTOK * DDIM, NTOK, 0, 512);
    norm_kernel<<<16384, 256, 0, stream>>>(out, Z1, Z2);
  } else if (ws_size >= WS_C512) {
    // ---------------- Plan C: chunked over j, recompute S ----------------
    const int CHJ = (ws_size >= WS_C2048) ? 2048 : (ws_size >= WS_C1024) ? 1024 : 512;
    f16* P1c = (f16*)(ws + (size_t)68157440);                            // NTOK x CHJ
    f16* P2c = (f16*)(ws + (size_t)68157440 + (size_t)NTOK * CHJ * 2);   // CHJ x NTOK

    hipMemsetAsync(row_ss, 0, 4 * NTOK * sizeof(float), stream);  // row_ss,col_ss + Z1,Z2 regions
    hipMemsetAsync(Z1, 0, 2 * NTOK * sizeof(float), stream);
    prep_kernel<<<dim3(32, 256, 2), dim3(32, 8), 0, stream>>>(im, aud, im_h, imT, aud_h, audT);
    pass1_kernel<<<4096, 256, 0, stream>>>(im_h, aud_h, row_ss, col_ss);
    scales_kernel<<<NTOK / 256, 256, 0, stream>>>(row_ss, col_ss, s1p, s2p);
    const int nchunk = NTOK / CHJ;
    for (int cj = 0; cj < nchunk; ++cj) {
      const int j0 = cj * CHJ;
      pass2c_kernel<<<dim3(64, CHJ / 128), 256, 0, stream>>>(im_h, aud_h, s1p, s2p, P1c, P2c,
                                                             Z1, Z2, j0, CHJ);
      // im_rec += P1c @ (audT rows, k-offset j0)^T   [K-split accumulation]
      gemm_out_kernel<<<512, 256, 0, stream>>>(P1c, CHJ, audT + j0, NTOK, out, CHJ, cj > 0, 512);
      // aud_rec rows [j0, j0+CHJ) = P2c @ imT^T      [full K]
      gemm_out_kernel<<<(CHJ / 128) * 8, 256, 0, stream>>>(P2c, NTOK, imT, NTOK,
                                                           out + (size_t)NTOK * DDIM +
                                                               (size_t)j0 * DDIM,
                                                           NTOK, 0, (CHJ / 128) * 8);
    }
    norm_kernel<<<16384, 256, 0, stream>>>(out, Z1, Z2);
  } else {
    // diagnostic sentinel: ws too small for any plan
    fill_kernel<<<(2u * NTOK * DDIM + 255) / 256, 256, 0, stream>>>(out, 1234.5f,
                                                                    (size_t)2 * NTOK * DDIM);
  }
}

// Round 4
// 842.566 us; speedup vs baseline: 1.4106x; 1.4106x over previous
//
#include <hip/hip_runtime.h>
#include <stdint.h>
#include <stddef.h>

#define NTOK 8192
#define DDIM 1024

// Plan F: single S pass, Sb materialized (193 MB).
#define WS_F 202375168ull
// Plan C: chunked recompute fallback tiers.
#define WS_C2048 135266304ull
#define WS_C1024 101711872ull
#define WS_C512   84934656ull

using f16   = _Float16;
using f16x8 = __attribute__((ext_vector_type(8))) _Float16;
using f32x4 = __attribute__((ext_vector_type(4))) float;

// ---------- async global->LDS (16B), linear LDS dest, swizzled global src ----------
__device__ __forceinline__ void gload16(const void* g, void* l) {
  __builtin_amdgcn_global_load_lds(
      (const __attribute__((address_space(1))) void*)g,
      (__attribute__((address_space(3))) void*)l, 16, 0, 0);
}

// Stage 128 x 64 f16 tile from row-major src (ld elems) into linear LDS [128][64].
// LDS 16B-chunk (r,c) holds global chunk (r, c ^ (r&7))  (rule #21: swizzle src+read).
__device__ __forceinline__ void stage_tile(const f16* __restrict__ src, int ld,
                                           int row0, int k0, f16* lds, int tid) {
#pragma unroll
  for (int base = 0; base < 1024; base += 256) {
    const int cl = base + tid;
    const int r = cl >> 3;
    const int cs = (cl & 7) ^ (r & 7);
    gload16(src + (size_t)(row0 + r) * ld + k0 + cs * 8, (char*)lds + (size_t)cl * 16);
  }
}

// Read one 8-f16 operand fragment (row r, k-chunk kc) with matching swizzle.
__device__ __forceinline__ f16x8 frag_ld(const f16* lds, int r, int kc) {
  const int c = kc ^ (r & 7);
  return *(const f16x8*)((const char*)lds + r * 128 + c * 16);
}

// XCD-aware chunked swizzle, bijective when nwg % 8 == 0.
__device__ __forceinline__ int xcd_swz(int bid, int nwg) {
  return (bid & 7) * (nwg >> 3) + (bid >> 3);
}

// ---------- prep: f32 -> f16, plus transposed f16 copy ----------
__global__ void prep_kernel(const float* __restrict__ inA, const float* __restrict__ inB,
                            f16* __restrict__ nA, f16* __restrict__ tA,
                            f16* __restrict__ nB, f16* __restrict__ tB) {
  const float* in = blockIdx.z ? inB : inA;
  f16* nrm = blockIdx.z ? nB : nA;
  f16* trp = blockIdx.z ? tB : tA;
  __shared__ float tile[32][33];
  const int c0 = blockIdx.x * 32;
  const int r0 = blockIdx.y * 32;
  const int tx = threadIdx.x, ty = threadIdx.y;
#pragma unroll
  for (int rr = 0; rr < 32; rr += 8) {
    const int r = r0 + rr + ty;
    const float v = in[(size_t)r * DDIM + c0 + tx];
    tile[rr + ty][tx] = v;
    nrm[(size_t)r * DDIM + c0 + tx] = (f16)v;
  }
  __syncthreads();
#pragma unroll
  for (int rr = 0; rr < 32; rr += 8) {
    trp[(size_t)(c0 + rr + ty) * NTOK + r0 + tx] = (f16)tile[tx][rr + ty];
  }
}

// ---------- core MFMA macro-body: 128x128 tile over K range, NT layout ----------
#define GEMM_CORE_R(Asrc, lda, Bsrc, ldb, K0, K1)                                     \
  for (int k0 = (K0); k0 < (K1); k0 += 64) {                                          \
    __syncthreads();                                                                  \
    stage_tile(Asrc, lda, row0, k0, Al, tid);                                         \
    stage_tile(Bsrc, ldb, col0, k0, Bl, tid);                                         \
    __syncthreads();                                                                  \
    _Pragma("unroll")                                                                 \
    for (int kk = 0; kk < 2; ++kk) {                                                  \
      f16x8 a[4], b[4];                                                               \
      _Pragma("unroll")                                                               \
      for (int m = 0; m < 4; ++m) a[m] = frag_ld(Al, wr + m * 16 + l15, kk * 4 + lg); \
      _Pragma("unroll")                                                               \
      for (int n = 0; n < 4; ++n) b[n] = frag_ld(Bl, wc + n * 16 + l15, kk * 4 + lg); \
      _Pragma("unroll")                                                               \
      for (int m = 0; m < 4; ++m)                                                     \
        _Pragma("unroll")                                                             \
        for (int n = 0; n < 4; ++n)                                                   \
          acc[m][n] = __builtin_amdgcn_mfma_f32_16x16x32_f16(a[m], b[n], acc[m][n], 0, 0, 0); \
    }                                                                                 \
  }
#define GEMM_CORE(Asrc, lda, Bsrc, ldb, KLEN) GEMM_CORE_R(Asrc, lda, Bsrc, ldb, 0, KLEN)

// ---------- Plan F: S-GEMM, leaky, row/col sum-sq, store Sb (f16) ----------
__global__ __launch_bounds__(256, 2)
void sgemm_kernel(const f16* __restrict__ A, const f16* __restrict__ B,
                  float* __restrict__ row_ss, float* __restrict__ col_ss,
                  f16* __restrict__ Sb) {
  __shared__ __align__(16) char smem[128 * 136 * 2];  // staging (32KB) unioned with repack
  f16* Al = (f16*)smem;
  f16* Bl = (f16*)(smem + 16384);
  f16* RP = (f16*)smem;  // 128 x 136 f16
  const int tid = threadIdx.x;
  const int lane = tid & 63, wid = tid >> 6;
  const int wr = (wid >> 1) * 64, wc = (wid & 1) * 64;
  const int l15 = lane & 15, lg = lane >> 4;
  const int swz = xcd_swz(blockIdx.x, 4096);
  const int row0 = (swz & 63) * 128, col0 = (swz >> 6) * 128;
  f32x4 acc[4][4];
#pragma unroll
  for (int m = 0; m < 4; ++m)
#pragma unroll
    for (int n = 0; n < 4; ++n) acc[m][n] = (f32x4){0.f, 0.f, 0.f, 0.f};

  GEMM_CORE(A, DDIM, B, DDIM, DDIM)

  // leaky in place
#pragma unroll
  for (int m = 0; m < 4; ++m)
#pragma unroll
    for (int n = 0; n < 4; ++n)
#pragma unroll
      for (int q = 0; q < 4; ++q) {
        const float v = acc[m][n][q];
        acc[m][n][q] = v > 0.f ? v : 0.1f * v;
      }
  // sum-of-squares reductions (registers + shfl only)
  float cpart[4] = {0.f, 0.f, 0.f, 0.f};
#pragma unroll
  for (int m = 0; m < 4; ++m) {
    float rpart[4] = {0.f, 0.f, 0.f, 0.f};
#pragma unroll
    for (int n = 0; n < 4; ++n) {
#pragma unroll
      for (int q = 0; q < 4; ++q) {
        const float v2 = acc[m][n][q] * acc[m][n][q];
        rpart[q] += v2;
        cpart[n] += v2;
      }
    }
#pragma unroll
    for (int q = 0; q < 4; ++q) {
      float s = rpart[q];
      s += __shfl_xor(s, 1, 64);
      s += __shfl_xor(s, 2, 64);
      s += __shfl_xor(s, 4, 64);
      s += __shfl_xor(s, 8, 64);
      if (l15 == 0) atomicAdd(&row_ss[row0 + wr + m * 16 + lg * 4 + q], s);
    }
  }
#pragma unroll
  for (int n = 0; n < 4; ++n) {
    float s = cpart[n];
    s += __shfl_xor(s, 16, 64);
    s += __shfl_xor(s, 32, 64);
    if (lg == 0) atomicAdd(&col_ss[col0 + wc + n * 16 + l15], s);
  }
  // ---- repack + coalesced store: Sb[i,j] ----
  __syncthreads();
#pragma unroll
  for (int m = 0; m < 4; ++m)
#pragma unroll
    for (int n = 0; n < 4; ++n)
#pragma unroll
      for (int q = 0; q < 4; ++q)
        RP[(wr + m * 16 + lg * 4 + q) * 136 + wc + n * 16 + l15] = (f16)acc[m][n][q];
  __syncthreads();
#pragma unroll
  for (int it = 0; it < 8; ++it) {
    const int r = it * 16 + (tid >> 4);
    const int c8 = (tid & 15) * 8;
    *(f16x8*)(Sb + (size_t)(row0 + r) * NTOK + col0 + c8) = *(const f16x8*)(RP + r * 136 + c8);
  }
}

// ---------- scales: 6*log2(e) / (sqrt(ss)+eps) ----------
__global__ void scales_kernel(const float* __restrict__ row_ss, const float* __restrict__ col_ss,
                              float* __restrict__ s1p, float* __restrict__ s2p) {
  const int i = blockIdx.x * 256 + threadIdx.x;
  const float c = 6.0f * 1.4426950408889634f;
  s1p[i] = c / (sqrtf(row_ss[i]) + 1e-8f);
  s2p[i] = c / (sqrtf(col_ss[i]) + 1e-8f);
}

// ---------- Plan F: transpose+exp chunk: P2c[jl, i] = exp2(Sb[i, j0c+jl]*s2), Z2 fused ----------
__global__ __launch_bounds__(256)
void texp_kernel(const f16* __restrict__ Sb, f16* __restrict__ P2c,
                 const float* __restrict__ s2p, float* __restrict__ Z2, int j0c) {
  __shared__ float T[128][33];
  const int t = threadIdx.x;
  const int i0 = blockIdx.x * 128;       // i supertile
  const int jc = blockIdx.y * 32;        // j offset within chunk
  const int jg = j0c + jc;               // global j base
  // read phase: 128 rows x 32 f16 (64B full lines)
#pragma unroll
  for (int it = 0; it < 2; ++it) {
    const int lin = it * 256 + t;
    const int r = lin >> 2, c8 = (lin & 3) * 8;
    const f16x8 v = *(const f16x8*)(Sb + (size_t)(i0 + r) * NTOK + jg + c8);
#pragma unroll
    for (int e = 0; e < 8; ++e) T[r][c8 + e] = (float)v[e];
  }
  __syncthreads();
  // write phase: 32 rows (j) x 128 i (256B lines), exp2 + Z2 partial
#pragma unroll
  for (int it = 0; it < 2; ++it) {
    const int lin = it * 256 + t;
    const int j = lin >> 4, ic = lin & 15;
    const float s = s2p[jg + j];
    f16x8 o;
    float sum = 0.f;
#pragma unroll
    for (int e = 0; e < 8; ++e) {
      const float p = exp2f(T[ic * 8 + e][j] * s);
      o[e] = (f16)p;
      sum += (float)o[e];  // sum the f16-rounded value: consistent with GEMM input
    }
    *(f16x8*)(P2c + (size_t)(jc + j) * NTOK + i0 + ic * 8) = o;
    sum += __shfl_xor(sum, 1, 64);
    sum += __shfl_xor(sum, 2, 64);
    sum += __shfl_xor(sum, 4, 64);
    sum += __shfl_xor(sum, 8, 64);
    if ((t & 15) == 0) atomicAdd(&Z2[jg + j], sum);
  }
}

// ---------- Plan F: gemm2 chunk: out_aud[chunk rows] += P2c @ imT^T, split-K=4, atomic ----------
__global__ __launch_bounds__(256, 2)
void gemm2_kernel(const f16* __restrict__ A, const f16* __restrict__ Bt,
                  float* __restrict__ C) {
  __shared__ __align__(16) f16 Al[128 * 64];
  __shared__ __align__(16) f16 Bl[128 * 64];
  const int tid = threadIdx.x;
  const int lane = tid & 63, wid = tid >> 6;
  const int wr = (wid >> 1) * 64, wc = (wid & 1) * 64;
  const int l15 = lane & 15, lg = lane >> 4;
  const int swz = xcd_swz(blockIdx.x, 512);
  const int tile = swz >> 2, kq = swz & 3;
  const int row0 = (tile >> 3) * 128, col0 = (tile & 7) * 128;
  f32x4 acc[4][4];
#pragma unroll
  for (int m = 0; m < 4; ++m)
#pragma unroll
    for (int n = 0; n < 4; ++n) acc[m][n] = (f32x4){0.f, 0.f, 0.f, 0.f};

  GEMM_CORE_R(A, NTOK, Bt, NTOK, kq * 2048, kq * 2048 + 2048)

#pragma unroll
  for (int m = 0; m < 4; ++m)
#pragma unroll
    for (int n = 0; n < 4; ++n) {
      const int ccol = col0 + wc + n * 16 + l15;
#pragma unroll
      for (int q = 0; q < 4; ++q) {
        const int crow = row0 + wr + m * 16 + lg * 4 + q;
        atomicAdd(&C[(size_t)crow * DDIM + ccol], acc[m][n][q]);
      }
    }
}

// ---------- Plan F: in-place P1 = exp2(Sb*scale_row), Z1 = row sum ----------
__global__ __launch_bounds__(256, 8)
void expz_kernel(f16* __restrict__ M, const float* __restrict__ s1p, float* __restrict__ Z1) {
  const int wid = threadIdx.x >> 6, lane = threadIdx.x & 63;
  const int row = blockIdx.x * 4 + wid;
  const float s = s1p[row];
  f16* rp = M + (size_t)row * NTOK;
  float acc = 0.f;
#pragma unroll
  for (int c = 0; c < 16; ++c) {
    f16x8* p = (f16x8*)(rp + (c * 64 + lane) * 8);
    f16x8 v = *p;
    f16x8 o;
#pragma unroll
    for (int e = 0; e < 8; ++e) {
      o[e] = (f16)exp2f((float)v[e] * s);
      acc += (float)o[e];  // sum the f16-rounded value: consistent with GEMM input
    }
    *p = o;
  }
#pragma unroll
  for (int d = 1; d < 64; d <<= 1) acc += __shfl_xor(acc, d, 64);
  if (lane == 0) Z1[row] = acc;
}

// ---------- Plan C: pass1 (S-GEMM + row/col sum-sq only) ----------
__global__ __launch_bounds__(256, 2)
void pass1_kernel(const f16* __restrict__ A, const f16* __restrict__ B,
                  float* __restrict__ row_ss, float* __restrict__ col_ss) {
  __shared__ __align__(16) f16 Al[128 * 64];
  __shared__ __align__(16) f16 Bl[128 * 64];
  const int tid = threadIdx.x;
  const int lane = tid & 63, wid = tid >> 6;
  const int wr = (wid >> 1) * 64, wc = (wid & 1) * 64;
  const int l15 = lane & 15, lg = lane >> 4;
  const int swz = xcd_swz(blockIdx.x, 4096);
  const int row0 = (swz & 63) * 128, col0 = (swz >> 6) * 128;
  f32x4 acc[4][4];
#pragma unroll
  for (int m = 0; m < 4; ++m)
#pragma unroll
    for (int n = 0; n < 4; ++n) acc[m][n] = (f32x4){0.f, 0.f, 0.f, 0.f};

  GEMM_CORE(A, DDIM, B, DDIM, DDIM)

  float cpart[4] = {0.f, 0.f, 0.f, 0.f};
#pragma unroll
  for (int m = 0; m < 4; ++m) {
    float rpart[4] = {0.f, 0.f, 0.f, 0.f};
#pragma unroll
    for (int n = 0; n < 4; ++n) {
#pragma unroll
      for (int q = 0; q < 4; ++q) {
        float v = acc[m][n][q];
        v = v > 0.f ? v : 0.1f * v;
        const float v2 = v * v;
        rpart[q] += v2;
        cpart[n] += v2;
      }
    }
#pragma unroll
    for (int q = 0; q < 4; ++q) {
      float s = rpart[q];
      s += __shfl_xor(s, 1, 64);
      s += __shfl_xor(s, 2, 64);
      s += __shfl_xor(s, 4, 64);
      s += __shfl_xor(s, 8, 64);
      if (l15 == 0) atomicAdd(&row_ss[row0 + wr + m * 16 + lg * 4 + q], s);
    }
  }
#pragma unroll
  for (int n = 0; n < 4; ++n) {
    float s = cpart[n];
    s += __shfl_xor(s, 16, 64);
    s += __shfl_xor(s, 32, 64);
    if (lg == 0) atomicAdd(&col_ss[col0 + wc + n * 16 + l15], s);
  }
}

// ---------- Plan C: per-j-chunk recompute; emit P1c [NTOK x CHJ] + P2c [CHJ x NTOK], Z sums ----------
__global__ __launch_bounds__(256, 2)
void pass2c_kernel(const f16* __restrict__ A, const f16* __restrict__ B,
                   const float* __restrict__ s1p, const float* __restrict__ s2p,
                   f16* __restrict__ P1c, f16* __restrict__ P2c,
                   float* __restrict__ Z1, float* __restrict__ Z2, int j0, int CHJ) {
  __shared__ __align__(16) char smem[128 * 136 * 2];
  f16* Al = (f16*)smem;
  f16* Bl = (f16*)(smem + 16384);
  f16* RP = (f16*)smem;
  const int tid = threadIdx.x;
  const int lane = tid & 63, wid = tid >> 6;
  const int wr = (wid >> 1) * 64, wc = (wid & 1) * 64;
  const int l15 = lane & 15, lg = lane >> 4;
  const int row0 = blockIdx.x * 128;            // global i
  const int col0loc = blockIdx.y * 128;         // local j within chunk
  const int col0 = j0 + col0loc;                // global j (for B operand + scales)
  f32x4 acc[4][4];
#pragma unroll
  for (int m = 0; m < 4; ++m)
#pragma unroll
    for (int n = 0; n < 4; ++n) acc[m][n] = (f32x4){0.f, 0.f, 0.f, 0.f};

  GEMM_CORE(A, DDIM, B, DDIM, DDIM)

#pragma unroll
  for (int m = 0; m < 4; ++m)
#pragma unroll
    for (int n = 0; n < 4; ++n)
#pragma unroll
      for (int q = 0; q < 4; ++q) {
        const float v = acc[m][n][q];
        acc[m][n][q] = v > 0.f ? v : 0.1f * v;
      }
  float sr[4][4], sc[4];
#pragma unroll
  for (int m = 0; m < 4; ++m)
#pragma unroll
    for (int q = 0; q < 4; ++q) sr[m][q] = s1p[row0 + wr + m * 16 + lg * 4 + q];
#pragma unroll
  for (int n = 0; n < 4; ++n) sc[n] = s2p[col0 + wc + n * 16 + l15];

  __syncthreads();
#pragma unroll
  for (int m = 0; m < 4; ++m)
#pragma unroll
    for (int n = 0; n < 4; ++n)
#pragma unroll
      for (int q = 0; q < 4; ++q) {
        const float p = exp2f(acc[m][n][q] * sr[m][q]);
        RP[(wr + m * 16 + lg * 4 + q) * 136 + wc + n * 16 + l15] = (f16)p;
      }
  __syncthreads();
#pragma unroll
  for (int it = 0; it < 8; ++it) {
    const int r = it * 16 + (tid >> 4);
    const int c8 = (tid & 15) * 8;
    const f16x8 v = *(const f16x8*)(RP + r * 136 + c8);
    float s = 0.f;
#pragma unroll
    for (int e = 0; e < 8; ++e) s += (float)v[e];
    *(f16x8*)(P1c + (size_t)(row0 + r) * CHJ + col0loc + c8) = v;
    s += __shfl_xor(s, 1, 64);
    s += __shfl_xor(s, 2, 64);
    s += __shfl_xor(s, 4, 64);
    s += __shfl_xor(s, 8, 64);
    if ((tid & 15) == 0) atomicAdd(&Z1[row0 + r], s);
  }
  __syncthreads();
#pragma unroll
  for (int m = 0; m < 4; ++m)
#pragma unroll
    for (int n = 0; n < 4; ++n)
#pragma unroll
      for (int q = 0; q < 4; ++q) {
        const float p = exp2f(acc[m][n][q] * sc[n]);
        RP[(wc + n * 16 + l15) * 136 + wr + m * 16 + lg * 4 + q] = (f16)p;
      }
  __syncthreads();
#pragma unroll
  for (int it = 0; it < 8; ++it) {
    const int r = it * 16 + (tid >> 4);
    const int c8 = (tid & 15) * 8;
    const f16x8 v = *(const f16x8*)(RP + r * 136 + c8);
    float s = 0.f;
#pragma unroll
    for (int e = 0; e < 8; ++e) s += (float)v[e];
    *(f16x8*)(P2c + (size_t)(col0loc + r) * NTOK + row0 + c8) = v;
    s += __shfl_xor(s, 1, 64);
    s += __shfl_xor(s, 2, 64);
    s += __shfl_xor(s, 4, 64);
    s += __shfl_xor(s, 8, 64);
    if ((tid & 15) == 0) atomicAdd(&Z2[col0 + r], s);
  }
}

// ---------- output GEMM: C tile (+)= A[M,K] @ Bt[N,K]^T, C f32 ld=DDIM. 1D grid, swizzled ----------
__global__ __launch_bounds__(256, 2)
void gemm_out_kernel(const f16* __restrict__ A, int lda,
                     const f16* __restrict__ Bt, int ldb,
                     float* __restrict__ C, int K, int beta, int nwg) {
  __shared__ __align__(16) f16 Al[128 * 64];
  __shared__ __align__(16) f16 Bl[128 * 64];
  const int tid = threadIdx.x;
  const int lane = tid & 63, wid = tid >> 6;
  const int wr = (wid >> 1) * 64, wc = (wid & 1) * 64;
  const int l15 = lane & 15, lg = lane >> 4;
  const int swz = xcd_swz(blockIdx.x, nwg);
  const int row0 = (swz >> 3) * 128, col0 = (swz & 7) * 128;
  f32x4 acc[4][4];
#pragma unroll
  for (int m = 0; m < 4; ++m)
#pragma unroll
    for (int n = 0; n < 4; ++n) acc[m][n] = (f32x4){0.f, 0.f, 0.f, 0.f};

  GEMM_CORE(A, lda, Bt, ldb, K)

#pragma unroll
  for (int m = 0; m < 4; ++m)
#pragma unroll
    for (int n = 0; n < 4; ++n) {
      const int ccol = col0 + wc + n * 16 + l15;
#pragma unroll
      for (int q = 0; q < 4; ++q) {
        const int crow = row0 + wr + m * 16 + lg * 4 + q;
        const size_t idx = (size_t)crow * DDIM + ccol;
        const float v = acc[m][n][q];
        C[idx] = beta ? C[idx] + v : v;
      }
    }
}

// ---------- final normalization by 1/Z ----------
__global__ void norm_kernel(float* __restrict__ out, const float* __restrict__ Z1,
                            const float* __restrict__ Z2) {
  const size_t idx = (size_t)blockIdx.x * 256 + threadIdx.x;  // float4 index
  const size_t e = idx * 4;
  const size_t half = (size_t)NTOK * DDIM;
  const float* Z = (e < half) ? Z1 : Z2;
  const int r = (int)((e >> 10) & (NTOK - 1));
  const float inv = 1.0f / Z[r];
  f32x4* o = (f32x4*)out;
  f32x4 v = o[idx];
  v.x *= inv; v.y *= inv; v.z *= inv; v.w *= inv;
  o[idx] = v;
}

__global__ void fill_kernel(float* __restrict__ out, float v, size_t n) {
  const size_t i = (size_t)blockIdx.x * 256 + threadIdx.x;
  if (i < n) out[i] = v;
}

extern "C" void kernel_launch(void* const* d_in, const int* in_sizes, int n_in,
                              void* d_out, int out_size, void* d_ws, size_t ws_size,
                              hipStream_t stream) {
  const float* im = (const float*)d_in[0];
  const float* aud = (const float*)d_in[1];
  float* out = (float*)d_out;
  char* ws = (char*)d_ws;

  // shared layout
  f16* im_h  = (f16*)(ws);                       // 16 MB; dead after S-GEMM
  f16* aud_h = (f16*)(ws + (size_t)16777216);    // 16 MB; dead after S-GEMM
  f16* imT   = (f16*)(ws + (size_t)33554432);    // 16 MB
  f16* audT  = (f16*)(ws + (size_t)50331648);    // 16 MB
  float* row_ss = (float*)(ws + (size_t)67108864);
  float* col_ss = (float*)(ws + (size_t)67108864 + 32768);
  float* Z1     = (float*)(ws + (size_t)67108864 + 65536);
  float* Z2     = (float*)(ws + (size_t)67108864 + 98304);
  float* s1p    = (float*)(ws + (size_t)67108864 + 131072);
  float* s2p    = (float*)(ws + (size_t)67108864 + 163840);

  if (ws_size >= WS_F) {
    // ---------------- Plan F: single S-GEMM, Sb materialized, chunked col path ----------------
    f16* Sb  = (f16*)(ws + (size_t)68157440);  // 8192x8192 f16 (128 MB); becomes P1 in place
    f16* P2c = (f16*)(ws);                     // 2048x8192 f16 (32 MB) over im_h|aud_h

    hipMemsetAsync(row_ss, 0, 2 * NTOK * sizeof(float), stream);              // row_ss, col_ss
    hipMemsetAsync(Z2, 0, NTOK * sizeof(float), stream);                      // Z2 (atomic)
    hipMemsetAsync(out + (size_t)NTOK * DDIM, 0, (size_t)NTOK * DDIM * 4, stream);  // aud_rec
    prep_kernel<<<dim3(32, 256, 2), dim3(32, 8), 0, stream>>>(im, aud, im_h, imT, aud_h, audT);
    sgemm_kernel<<<4096, 256, 0, stream>>>(im_h, aud_h, row_ss, col_ss, Sb);
    scales_kernel<<<NTOK / 256, 256, 0, stream>>>(row_ss, col_ss, s1p, s2p);
    for (int c = 0; c < 4; ++c) {
      const int j0c = c * 2048;
      texp_kernel<<<dim3(64, 64), 256, 0, stream>>>(Sb, P2c, s2p, Z2, j0c);
      gemm2_kernel<<<512, 256, 0, stream>>>(P2c, imT,
                                            out + (size_t)NTOK * DDIM + (size_t)j0c * DDIM);
    }
    expz_kernel<<<NTOK / 4, 256, 0, stream>>>(Sb, s1p, Z1);
    gemm_out_kernel<<<512, 256, 0, stream>>>(Sb, NTOK, audT, NTOK, out, NTOK, 0, 512);
    norm_kernel<<<16384, 256, 0, stream>>>(out, Z1, Z2);
  } else if (ws_size >= WS_C512) {
    // ---------------- Plan C: chunked over j, recompute S (fallback) ----------------
    const int CHJ = (ws_size >= WS_C2048) ? 2048 : (ws_size >= WS_C1024) ? 1024 : 512;
    f16* P1c = (f16*)(ws + (size_t)68157440);
    f16* P2c = (f16*)(ws + (size_t)68157440 + (size_t)NTOK * CHJ * 2);

    hipMemsetAsync(row_ss, 0, 2 * NTOK * sizeof(float), stream);
    hipMemsetAsync(Z1, 0, NTOK * sizeof(float), stream);
    hipMemsetAsync(Z2, 0, NTOK * sizeof(float), stream);
    prep_kernel<<<dim3(32, 256, 2), dim3(32, 8), 0, stream>>>(im, aud, im_h, imT, aud_h, audT);
    pass1_kernel<<<4096, 256, 0, stream>>>(im_h, aud_h, row_ss, col_ss);
    scales_kernel<<<NTOK / 256, 256, 0, stream>>>(row_ss, col_ss, s1p, s2p);
    const int nchunk = NTOK / CHJ;
    for (int cj = 0; cj < nchunk; ++cj) {
      const int j0 = cj * CHJ;
      pass2c_kernel<<<dim3(64, CHJ / 128), 256, 0, stream>>>(im_h, aud_h, s1p, s2p, P1c, P2c,
                                                             Z1, Z2, j0, CHJ);
      gemm_out_kernel<<<512, 256, 0, stream>>>(P1c, CHJ, audT + j0, NTOK, out, CHJ, cj > 0, 512);
      gemm_out_kernel<<<(CHJ / 128) * 8, 256, 0, stream>>>(P2c, NTOK, imT, NTOK,
                                                           out + (size_t)NTOK * DDIM +
                                                               (size_t)j0 * DDIM,
                                                           NTOK, 0, (CHJ / 128) * 8);
    }
    norm_kernel<<<16384, 256, 0, stream>>>(out, Z1, Z2);
  } else {
    // diagnostic sentinel: ws too small for any plan
    fill_kernel<<<(2u * NTOK * DDIM + 255) / 256, 256, 0, stream>>>(out, 1234.5f,
                                                                    (size_t)2 * NTOK * DDIM);
  }
}

// Round 8
// 805.373 us; speedup vs baseline: 1.4757x; 1.0462x over previous
//
#include <hip/hip_runtime.h>
#include <stdint.h>
#include <stddef.h>

#define NTOK 8192
#define DDIM 1024

// Plan F: single S pass, Sb materialized (193 MB).
#define WS_F 202375168ull
// Plan C: chunked recompute fallback tiers.
#define WS_C2048 135266304ull
#define WS_C1024 101711872ull
#define WS_C512   84934656ull

using f16   = _Float16;
using f16x8 = __attribute__((ext_vector_type(8))) _Float16;
using f32x4 = __attribute__((ext_vector_type(4))) float;

// ---------- async global->LDS (16B), linear LDS dest, swizzled global src ----------
__device__ __forceinline__ void gload16(const void* g, void* l) {
  __builtin_amdgcn_global_load_lds(
      (const __attribute__((address_space(1))) void*)g,
      (__attribute__((address_space(3))) void*)l, 16, 0, 0);
}

// Stage 128 x 64 f16 tile from row-major src (ld elems) into linear LDS [128][64].
// LDS 16B-chunk (r,c) holds global chunk (r, c ^ (r&7))  (rule #21: swizzle src+read).
__device__ __forceinline__ void stage_tile(const f16* __restrict__ src, int ld,
                                           int row0, int k0, f16* lds, int tid) {
#pragma unroll
  for (int base = 0; base < 1024; base += 256) {
    const int cl = base + tid;
    const int r = cl >> 3;
    const int cs = (cl & 7) ^ (r & 7);
    gload16(src + (size_t)(row0 + r) * ld + k0 + cs * 8, (char*)lds + (size_t)cl * 16);
  }
}

// Read one 8-f16 operand fragment (row r, k-chunk kc) with matching swizzle.
__device__ __forceinline__ f16x8 frag_ld(const f16* lds, int r, int kc) {
  const int c = kc ^ (r & 7);
  return *(const f16x8*)((const char*)lds + r * 128 + c * 16);
}

// XCD-aware chunked swizzle, bijective when nwg % 8 == 0.
__device__ __forceinline__ int xcd_swz(int bid, int nwg) {
  return (bid & 7) * (nwg >> 3) + (bid >> 3);
}

// ---------- prep: f32 -> f16, plus transposed f16 copy ----------
__global__ void prep_kernel(const float* __restrict__ inA, const float* __restrict__ inB,
                            f16* __restrict__ nA, f16* __restrict__ tA,
                            f16* __restrict__ nB, f16* __restrict__ tB) {
  const float* in = blockIdx.z ? inB : inA;
  f16* nrm = blockIdx.z ? nB : nA;
  f16* trp = blockIdx.z ? tB : tA;
  __shared__ float tile[32][33];
  const int c0 = blockIdx.x * 32;
  const int r0 = blockIdx.y * 32;
  const int tx = threadIdx.x, ty = threadIdx.y;
#pragma unroll
  for (int rr = 0; rr < 32; rr += 8) {
    const int r = r0 + rr + ty;
    const float v = in[(size_t)r * DDIM + c0 + tx];
    tile[rr + ty][tx] = v;
    nrm[(size_t)r * DDIM + c0 + tx] = (f16)v;
  }
  __syncthreads();
#pragma unroll
  for (int rr = 0; rr < 32; rr += 8) {
    trp[(size_t)(c0 + rr + ty) * NTOK + r0 + tx] = (f16)tile[tx][rr + ty];
  }
}

// ---------- core MFMA macro-body: 128x128 tile over K range, NT layout ----------
#define GEMM_CORE_R(Asrc, lda, Bsrc, ldb, K0, K1)                                     \
  for (int k0 = (K0); k0 < (K1); k0 += 64) {                                          \
    __syncthreads();                                                                  \
    stage_tile(Asrc, lda, row0, k0, Al, tid);                                         \
    stage_tile(Bsrc, ldb, col0, k0, Bl, tid);                                         \
    __syncthreads();                                                                  \
    _Pragma("unroll")                                                                 \
    for (int kk = 0; kk < 2; ++kk) {                                                  \
      f16x8 a[4], b[4];                                                               \
      _Pragma("unroll")                                                               \
      for (int m = 0; m < 4; ++m) a[m] = frag_ld(Al, wr + m * 16 + l15, kk * 4 + lg); \
      _Pragma("unroll")                                                               \
      for (int n = 0; n < 4; ++n) b[n] = frag_ld(Bl, wc + n * 16 + l15, kk * 4 + lg); \
      _Pragma("unroll")                                                               \
      for (int m = 0; m < 4; ++m)                                                     \
        _Pragma("unroll")                                                             \
        for (int n = 0; n < 4; ++n)                                                   \
          acc[m][n] = __builtin_amdgcn_mfma_f32_16x16x32_f16(a[m], b[n], acc[m][n], 0, 0, 0); \
    }                                                                                 \
  }
#define GEMM_CORE(Asrc, lda, Bsrc, ldb, KLEN) GEMM_CORE_R(Asrc, lda, Bsrc, ldb, 0, KLEN)

// ---------- Plan F: S-GEMM, leaky, row/col sum-sq, store Sb (f16) ----------
__global__ __launch_bounds__(256, 2)
void sgemm_kernel(const f16* __restrict__ A, const f16* __restrict__ B,
                  float* __restrict__ row_ss, float* __restrict__ col_ss,
                  f16* __restrict__ Sb) {
  __shared__ __align__(16) char smem[128 * 136 * 2];  // staging (32KB) unioned with repack
  f16* Al = (f16*)smem;
  f16* Bl = (f16*)(smem + 16384);
  f16* RP = (f16*)smem;  // 128 x 136 f16
  const int tid = threadIdx.x;
  const int lane = tid & 63, wid = tid >> 6;
  const int wr = (wid >> 1) * 64, wc = (wid & 1) * 64;
  const int l15 = lane & 15, lg = lane >> 4;
  const int swz = xcd_swz(blockIdx.x, 4096);
  const int row0 = (swz & 63) * 128, col0 = (swz >> 6) * 128;
  f32x4 acc[4][4];
#pragma unroll
  for (int m = 0; m < 4; ++m)
#pragma unroll
    for (int n = 0; n < 4; ++n) acc[m][n] = (f32x4){0.f, 0.f, 0.f, 0.f};

  GEMM_CORE(A, DDIM, B, DDIM, DDIM)

  // leaky in place
#pragma unroll
  for (int m = 0; m < 4; ++m)
#pragma unroll
    for (int n = 0; n < 4; ++n)
#pragma unroll
      for (int q = 0; q < 4; ++q) {
        const float v = acc[m][n][q];
        acc[m][n][q] = v > 0.f ? v : 0.1f * v;
      }
  // sum-of-squares reductions (registers + shfl only)
  float cpart[4] = {0.f, 0.f, 0.f, 0.f};
#pragma unroll
  for (int m = 0; m < 4; ++m) {
    float rpart[4] = {0.f, 0.f, 0.f, 0.f};
#pragma unroll
    for (int n = 0; n < 4; ++n) {
#pragma unroll
      for (int q = 0; q < 4; ++q) {
        const float v2 = acc[m][n][q] * acc[m][n][q];
        rpart[q] += v2;
        cpart[n] += v2;
      }
    }
#pragma unroll
    for (int q = 0; q < 4; ++q) {
      float s = rpart[q];
      s += __shfl_xor(s, 1, 64);
      s += __shfl_xor(s, 2, 64);
      s += __shfl_xor(s, 4, 64);
      s += __shfl_xor(s, 8, 64);
      if (l15 == 0) atomicAdd(&row_ss[row0 + wr + m * 16 + lg * 4 + q], s);
    }
  }
#pragma unroll
  for (int n = 0; n < 4; ++n) {
    float s = cpart[n];
    s += __shfl_xor(s, 16, 64);
    s += __shfl_xor(s, 32, 64);
    if (lg == 0) atomicAdd(&col_ss[col0 + wc + n * 16 + l15], s);
  }
  // ---- repack + coalesced store: Sb[i,j] ----
  __syncthreads();
#pragma unroll
  for (int m = 0; m < 4; ++m)
#pragma unroll
    for (int n = 0; n < 4; ++n)
#pragma unroll
      for (int q = 0; q < 4; ++q)
        RP[(wr + m * 16 + lg * 4 + q) * 136 + wc + n * 16 + l15] = (f16)acc[m][n][q];
  __syncthreads();
#pragma unroll
  for (int it = 0; it < 8; ++it) {
    const int r = it * 16 + (tid >> 4);
    const int c8 = (tid & 15) * 8;
    *(f16x8*)(Sb + (size_t)(row0 + r) * NTOK + col0 + c8) = *(const f16x8*)(RP + r * 136 + c8);
  }
}

// ---------- scales: 6*log2(e) / (sqrt(ss)+eps) ----------
__global__ void scales_kernel(const float* __restrict__ row_ss, const float* __restrict__ col_ss,
                              float* __restrict__ s1p, float* __restrict__ s2p) {
  const int i = blockIdx.x * 256 + threadIdx.x;
  const float c = 6.0f * 1.4426950408889634f;
  s1p[i] = c / (sqrtf(row_ss[i]) + 1e-8f);
  s2p[i] = c / (sqrtf(col_ss[i]) + 1e-8f);
}

// ---------- Plan F: fused dual-exp chunk kernel ----------
// Reads Sb tile (128 i x 64 j) once:
//   P1 in place:  Sb[i,j] <- exp2(Sb[i,j]*s1[i]),  Z1 += row sums
//   P2c transposed: P2c[jl,i] = exp2(S[i,j]*s2[j]), Z2 += col sums
__global__ __launch_bounds__(256)
void texp2_kernel(f16* __restrict__ Sb, f16* __restrict__ P2c,
                  const float* __restrict__ s1p, const float* __restrict__ s2p,
                  float* __restrict__ Z1, float* __restrict__ Z2, int j0c) {
  __shared__ f16 T[64][130];  // [j_local][i_local], pitch 130 breaks pow2 banks
  const int t = threadIdx.x;
  const int i0 = blockIdx.x * 128;
  const int jl = blockIdx.y * 64;     // j offset within chunk
  const int jg = j0c + jl;            // global j base
  // phase 1: coalesced read, P1 in place + Z1, stash raw S transposed in LDS
#pragma unroll
  for (int it = 0; it < 4; ++it) {
    const int lin = it * 256 + t;
    const int r = lin >> 3;            // 0..127 (i local)
    const int c8 = (lin & 7) * 8;      // 0..56 (j local)
    f16* addr = Sb + (size_t)(i0 + r) * NTOK + jg + c8;
    const f16x8 v = *(const f16x8*)addr;
    const float s1 = s1p[i0 + r];
    f16x8 o;
    float zp = 0.f;
#pragma unroll
    for (int e = 0; e < 8; ++e) {
      const float x = (float)v[e];
      T[c8 + e][r] = v[e];
      o[e] = (f16)exp2f(x * s1);
      zp += (float)o[e];  // sum f16-rounded value: consistent with GEMM input
    }
    *(f16x8*)addr = o;
    zp += __shfl_xor(zp, 1, 64);
    zp += __shfl_xor(zp, 2, 64);
    zp += __shfl_xor(zp, 4, 64);
    if ((t & 7) == 0) atomicAdd(&Z1[i0 + r], zp);
  }
  __syncthreads();
  // phase 2: transposed write P2c + Z2
#pragma unroll
  for (int it = 0; it < 4; ++it) {
    const int lin = it * 256 + t;
    const int jj = lin >> 4;           // 0..63 (j local)
    const int iof = (lin & 15) * 8;    // 0..120 (i local)
    const float s2 = s2p[jg + jj];
    f16x8 o;
    float zp = 0.f;
#pragma unroll
    for (int e = 0; e < 8; ++e) {
      const float x = (float)T[jj][iof + e];
      o[e] = (f16)exp2f(x * s2);
      zp += (float)o[e];
    }
    *(f16x8*)(P2c + (size_t)(jl + jj) * NTOK + i0 + iof) = o;
    zp += __shfl_xor(zp, 1, 64);
    zp += __shfl_xor(zp, 2, 64);
    zp += __shfl_xor(zp, 4, 64);
    zp += __shfl_xor(zp, 8, 64);
    if ((t & 15) == 0) atomicAdd(&Z2[jg + jj], zp);
  }
}

// ---------- Plan F: gemm2 chunk: out_aud[chunk rows] += (P2c @ imT^T) / Z2, split-K=4 ----------
__global__ __launch_bounds__(256, 2)
void gemm2_kernel(const f16* __restrict__ A, const f16* __restrict__ Bt,
                  float* __restrict__ C, const float* __restrict__ Zrow) {
  __shared__ __align__(16) f16 Al[128 * 64];
  __shared__ __align__(16) f16 Bl[128 * 64];
  const int tid = threadIdx.x;
  const int lane = tid & 63, wid = tid >> 6;
  const int wr = (wid >> 1) * 64, wc = (wid & 1) * 64;
  const int l15 = lane & 15, lg = lane >> 4;
  const int swz = xcd_swz(blockIdx.x, 512);
  const int tile = swz >> 2, kq = swz & 3;
  const int row0 = (tile >> 3) * 128, col0 = (tile & 7) * 128;
  f32x4 acc[4][4];
#pragma unroll
  for (int m = 0; m < 4; ++m)
#pragma unroll
    for (int n = 0; n < 4; ++n) acc[m][n] = (f32x4){0.f, 0.f, 0.f, 0.f};

  GEMM_CORE_R(A, NTOK, Bt, NTOK, kq * 2048, kq * 2048 + 2048)

#pragma unroll
  for (int m = 0; m < 4; ++m)
#pragma unroll
    for (int n = 0; n < 4; ++n) {
      const int ccol = col0 + wc + n * 16 + l15;
#pragma unroll
      for (int q = 0; q < 4; ++q) {
        const int crow = row0 + wr + m * 16 + lg * 4 + q;
        atomicAdd(&C[(size_t)crow * DDIM + ccol], acc[m][n][q] / Zrow[crow]);
      }
    }
}

// ---------- Plan C: pass1 (S-GEMM + row/col sum-sq only) ----------
__global__ __launch_bounds__(256, 2)
void pass1_kernel(const f16* __restrict__ A, const f16* __restrict__ B,
                  float* __restrict__ row_ss, float* __restrict__ col_ss) {
  __shared__ __align__(16) f16 Al[128 * 64];
  __shared__ __align__(16) f16 Bl[128 * 64];
  const int tid = threadIdx.x;
  const int lane = tid & 63, wid = tid >> 6;
  const int wr = (wid >> 1) * 64, wc = (wid & 1) * 64;
  const int l15 = lane & 15, lg = lane >> 4;
  const int swz = xcd_swz(blockIdx.x, 4096);
  const int row0 = (swz & 63) * 128, col0 = (swz >> 6) * 128;
  f32x4 acc[4][4];
#pragma unroll
  for (int m = 0; m < 4; ++m)
#pragma unroll
    for (int n = 0; n < 4; ++n) acc[m][n] = (f32x4){0.f, 0.f, 0.f, 0.f};

  GEMM_CORE(A, DDIM, B, DDIM, DDIM)

  float cpart[4] = {0.f, 0.f, 0.f, 0.f};
#pragma unroll
  for (int m = 0; m < 4; ++m) {
    float rpart[4] = {0.f, 0.f, 0.f, 0.f};
#pragma unroll
    for (int n = 0; n < 4; ++n) {
#pragma unroll
      for (int q = 0; q < 4; ++q) {
        float v = acc[m][n][q];
        v = v > 0.f ? v : 0.1f * v;
        const float v2 = v * v;
        rpart[q] += v2;
        cpart[n] += v2;
      }
    }
#pragma unroll
    for (int q = 0; q < 4; ++q) {
      float s = rpart[q];
      s += __shfl_xor(s, 1, 64);
      s += __shfl_xor(s, 2, 64);
      s += __shfl_xor(s, 4, 64);
      s += __shfl_xor(s, 8, 64);
      if (l15 == 0) atomicAdd(&row_ss[row0 + wr + m * 16 + lg * 4 + q], s);
    }
  }
#pragma unroll
  for (int n = 0; n < 4; ++n) {
    float s = cpart[n];
    s += __shfl_xor(s, 16, 64);
    s += __shfl_xor(s, 32, 64);
    if (lg == 0) atomicAdd(&col_ss[col0 + wc + n * 16 + l15], s);
  }
}

// ---------- Plan C: per-j-chunk recompute; emit P1c [NTOK x CHJ] + P2c [CHJ x NTOK], Z sums ----------
__global__ __launch_bounds__(256, 2)
void pass2c_kernel(const f16* __restrict__ A, const f16* __restrict__ B,
                   const float* __restrict__ s1p, const float* __restrict__ s2p,
                   f16* __restrict__ P1c, f16* __restrict__ P2c,
                   float* __restrict__ Z1, float* __restrict__ Z2, int j0, int CHJ) {
  __shared__ __align__(16) char smem[128 * 136 * 2];
  f16* Al = (f16*)smem;
  f16* Bl = (f16*)(smem + 16384);
  f16* RP = (f16*)smem;
  const int tid = threadIdx.x;
  const int lane = tid & 63, wid = tid >> 6;
  const int wr = (wid >> 1) * 64, wc = (wid & 1) * 64;
  const int l15 = lane & 15, lg = lane >> 4;
  const int row0 = blockIdx.x * 128;            // global i
  const int col0loc = blockIdx.y * 128;         // local j within chunk
  const int col0 = j0 + col0loc;                // global j (for B operand + scales)
  f32x4 acc[4][4];
#pragma unroll
  for (int m = 0; m < 4; ++m)
#pragma unroll
    for (int n = 0; n < 4; ++n) acc[m][n] = (f32x4){0.f, 0.f, 0.f, 0.f};

  GEMM_CORE(A, DDIM, B, DDIM, DDIM)

#pragma unroll
  for (int m = 0; m < 4; ++m)
#pragma unroll
    for (int n = 0; n < 4; ++n)
#pragma unroll
      for (int q = 0; q < 4; ++q) {
        const float v = acc[m][n][q];
        acc[m][n][q] = v > 0.f ? v : 0.1f * v;
      }
  float sr[4][4], sc[4];
#pragma unroll
  for (int m = 0; m < 4; ++m)
#pragma unroll
    for (int q = 0; q < 4; ++q) sr[m][q] = s1p[row0 + wr + m * 16 + lg * 4 + q];
#pragma unroll
  for (int n = 0; n < 4; ++n) sc[n] = s2p[col0 + wc + n * 16 + l15];

  __syncthreads();
#pragma unroll
  for (int m = 0; m < 4; ++m)
#pragma unroll
    for (int n = 0; n < 4; ++n)
#pragma unroll
      for (int q = 0; q < 4; ++q) {
        const float p = exp2f(acc[m][n][q] * sr[m][q]);
        RP[(wr + m * 16 + lg * 4 + q) * 136 + wc + n * 16 + l15] = (f16)p;
      }
  __syncthreads();
#pragma unroll
  for (int it = 0; it < 8; ++it) {
    const int r = it * 16 + (tid >> 4);
    const int c8 = (tid & 15) * 8;
    const f16x8 v = *(const f16x8*)(RP + r * 136 + c8);
    float s = 0.f;
#pragma unroll
    for (int e = 0; e < 8; ++e) s += (float)v[e];
    *(f16x8*)(P1c + (size_t)(row0 + r) * CHJ + col0loc + c8) = v;
    s += __shfl_xor(s, 1, 64);
    s += __shfl_xor(s, 2, 64);
    s += __shfl_xor(s, 4, 64);
    s += __shfl_xor(s, 8, 64);
    if ((tid & 15) == 0) atomicAdd(&Z1[row0 + r], s);
  }
  __syncthreads();
#pragma unroll
  for (int m = 0; m < 4; ++m)
#pragma unroll
    for (int n = 0; n < 4; ++n)
#pragma unroll
      for (int q = 0; q < 4; ++q) {
        const float p = exp2f(acc[m][n][q] * sc[n]);
        RP[(wc + n * 16 + l15) * 136 + wr + m * 16 + lg * 4 + q] = (f16)p;
      }
  __syncthreads();
#pragma unroll
  for (int it = 0; it < 8; ++it) {
    const int r = it * 16 + (tid >> 4);
    const int c8 = (tid & 15) * 8;
    const f16x8 v = *(const f16x8*)(RP + r * 136 + c8);
    float s = 0.f;
#pragma unroll
    for (int e = 0; e < 8; ++e) s += (float)v[e];
    *(f16x8*)(P2c + (size_t)(col0loc + r) * NTOK + row0 + c8) = v;
    s += __shfl_xor(s, 1, 64);
    s += __shfl_xor(s, 2, 64);
    s += __shfl_xor(s, 4, 64);
    s += __shfl_xor(s, 8, 64);
    if ((tid & 15) == 0) atomicAdd(&Z2[col0 + r], s);
  }
}

// ---------- output GEMM: C tile (+)= (A[M,K] @ Bt[N,K]^T) [/ Zrow], C f32 ld=DDIM ----------
__global__ __launch_bounds__(256, 2)
void gemm_out_kernel(const f16* __restrict__ A, int lda,
                     const f16* __restrict__ Bt, int ldb,
                     float* __restrict__ C, int K, int beta, int nwg,
                     const float* __restrict__ Zrow) {
  __shared__ __align__(16) f16 Al[128 * 64];
  __shared__ __align__(16) f16 Bl[128 * 64];
  const int tid = threadIdx.x;
  const int lane = tid & 63, wid = tid >> 6;
  const int wr = (wid >> 1) * 64, wc = (wid & 1) * 64;
  const int l15 = lane & 15, lg = lane >> 4;
  const int swz = xcd_swz(blockIdx.x, nwg);
  const int row0 = (swz >> 3) * 128, col0 = (swz & 7) * 128;
  f32x4 acc[4][4];
#pragma unroll
  for (int m = 0; m < 4; ++m)
#pragma unroll
    for (int n = 0; n < 4; ++n) acc[m][n] = (f32x4){0.f, 0.f, 0.f, 0.f};

  GEMM_CORE(A, lda, Bt, ldb, K)

#pragma unroll
  for (int m = 0; m < 4; ++m)
#pragma unroll
    for (int n = 0; n < 4; ++n) {
      const int ccol = col0 + wc + n * 16 + l15;
#pragma unroll
      for (int q = 0; q < 4; ++q) {
        const int crow = row0 + wr + m * 16 + lg * 4 + q;
        const size_t idx = (size_t)crow * DDIM + ccol;
        float v = acc[m][n][q];
        if (Zrow) v /= Zrow[crow];
        C[idx] = beta ? C[idx] + v : v;
      }
    }
}

// ---------- final normalization by 1/Z (Plan C only) ----------
__global__ void norm_kernel(float* __restrict__ out, const float* __restrict__ Z1,
                            const float* __restrict__ Z2) {
  const size_t idx = (size_t)blockIdx.x * 256 + threadIdx.x;  // float4 index
  const size_t e = idx * 4;
  const size_t half = (size_t)NTOK * DDIM;
  const float* Z = (e < half) ? Z1 : Z2;
  const int r = (int)((e >> 10) & (NTOK - 1));
  const float inv = 1.0f / Z[r];
  f32x4* o = (f32x4*)out;
  f32x4 v = o[idx];
  v.x *= inv; v.y *= inv; v.z *= inv; v.w *= inv;
  o[idx] = v;
}

__global__ void fill_kernel(float* __restrict__ out, float v, size_t n) {
  const size_t i = (size_t)blockIdx.x * 256 + threadIdx.x;
  if (i < n) out[i] = v;
}

extern "C" void kernel_launch(void* const* d_in, const int* in_sizes, int n_in,
                              void* d_out, int out_size, void* d_ws, size_t ws_size,
                              hipStream_t stream) {
  const float* im = (const float*)d_in[0];
  const float* aud = (const float*)d_in[1];
  float* out = (float*)d_out;
  char* ws = (char*)d_ws;

  // shared layout
  f16* im_h  = (f16*)(ws);                       // 16 MB; dead after S-GEMM
  f16* aud_h = (f16*)(ws + (size_t)16777216);    // 16 MB; dead after S-GEMM
  f16* imT   = (f16*)(ws + (size_t)33554432);    // 16 MB
  f16* audT  = (f16*)(ws + (size_t)50331648);    // 16 MB
  float* row_ss = (float*)(ws + (size_t)67108864);
  float* col_ss = (float*)(ws + (size_t)67108864 + 32768);
  float* Z1     = (float*)(ws + (size_t)67108864 + 65536);
  float* Z2     = (float*)(ws + (size_t)67108864 + 98304);
  float* s1p    = (float*)(ws + (size_t)67108864 + 131072);
  float* s2p    = (float*)(ws + (size_t)67108864 + 163840);

  if (ws_size >= WS_F) {
    // ---------------- Plan F: single S-GEMM, Sb materialized, fused exp/transpose ----------------
    f16* Sb  = (f16*)(ws + (size_t)68157440);  // 8192x8192 f16 (128 MB); becomes P1 in place
    f16* P2c = (f16*)(ws);                     // 2048x8192 f16 (32 MB) over im_h|aud_h

    hipMemsetAsync(row_ss, 0, 2 * NTOK * sizeof(float), stream);          // row_ss, col_ss
    hipMemsetAsync(Z1, 0, 2 * NTOK * sizeof(float), stream);              // Z1, Z2 (atomic)
    hipMemsetAsync(out + (size_t)NTOK * DDIM, 0, (size_t)NTOK * DDIM * 4, stream);  // aud_rec
    prep_kernel<<<dim3(32, 256, 2), dim3(32, 8), 0, stream>>>(im, aud, im_h, imT, aud_h, audT);
    sgemm_kernel<<<4096, 256, 0, stream>>>(im_h, aud_h, row_ss, col_ss, Sb);
    scales_kernel<<<NTOK / 256, 256, 0, stream>>>(row_ss, col_ss, s1p, s2p);
    for (int c = 0; c < 4; ++c) {
      const int j0c = c * 2048;
      texp2_kernel<<<dim3(64, 32), 256, 0, stream>>>(Sb, P2c, s1p, s2p, Z1, Z2, j0c);
      gemm2_kernel<<<512, 256, 0, stream>>>(P2c, imT,
                                            out + (size_t)NTOK * DDIM + (size_t)j0c * DDIM,
                                            Z2 + j0c);
    }
    // im_rec = (P1 @ audT^T) / Z1  (P1 = Sb in place)
    gemm_out_kernel<<<512, 256, 0, stream>>>(Sb, NTOK, audT, NTOK, out, NTOK, 0, 512, Z1);
  } else if (ws_size >= WS_C512) {
    // ---------------- Plan C: chunked over j, recompute S (fallback) ----------------
    const int CHJ = (ws_size >= WS_C2048) ? 2048 : (ws_size >= WS_C1024) ? 1024 : 512;
    f16* P1c = (f16*)(ws + (size_t)68157440);
    f16* P2c = (f16*)(ws + (size_t)68157440 + (size_t)NTOK * CHJ * 2);

    hipMemsetAsync(row_ss, 0, 2 * NTOK * sizeof(float), stream);
    hipMemsetAsync(Z1, 0, 2 * NTOK * sizeof(float), stream);
    prep_kernel<<<dim3(32, 256, 2), dim3(32, 8), 0, stream>>>(im, aud, im_h, imT, aud_h, audT);
    pass1_kernel<<<4096, 256, 0, stream>>>(im_h, aud_h, row_ss, col_ss);
    scales_kernel<<<NTOK / 256, 256, 0, stream>>>(row_ss, col_ss, s1p, s2p);
    const int nchunk = NTOK / CHJ;
    for (int cj = 0; cj < nchunk; ++cj) {
      const int j0 = cj * CHJ;
      pass2c_kernel<<<dim3(64, CHJ / 128), 256, 0, stream>>>(im_h, aud_h, s1p, s2p, P1c, P2c,
                                                             Z1, Z2, j0, CHJ);
      gemm_out_kernel<<<512, 256, 0, stream>>>(P1c, CHJ, audT + j0, NTOK, out, CHJ, cj > 0, 512,
                                               nullptr);
      gemm_out_kernel<<<(CHJ / 128) * 8, 256, 0, stream>>>(P2c, NTOK, imT, NTOK,
                                                           out + (size_t)NTOK * DDIM +
                                                               (size_t)j0 * DDIM,
                                                           NTOK, 0, (CHJ / 128) * 8, nullptr);
    }
    norm_kernel<<<16384, 256, 0, stream>>>(out, Z1, Z2);
  } else {
    // diagnostic sentinel: ws too small for any plan
    fill_kernel<<<(2u * NTOK * DDIM + 255) / 256, 256, 0, stream>>>(out, 1234.5f,
                                                                    (size_t)2 * NTOK * DDIM);
  }
}